// Round 8
// baseline (145.820 us; speedup 1.0000x reference)
//
#include <hip/hip_runtime.h>
#include <math.h>

// KDE Gaussian, bandwidth 0.1 — single fused persistent kernel.
//   out[b,m] = (1/norm_b) * sum_n exp(-50*||s[b,n]-l[m]||^2)
// exp(-50 d2) = exp2(W*d2); terms with t <= -14 culled (dropped mass ~1e-7
// normalized vs 9.4e-6 threshold).  Normalizer computed ANALYTICALLY:
//   norm_b = sum_n S(x_n)S(y_n),  S(u) = K*(erf(AE-sq*u)+erf(AE+sq*u))
// (separable lattice Gaussian sum; Poisson-summation error ~e^-88).
// Phase A (16 blocks): Morton counting-sort of 1024-sample segments into
// packed float2-SoA groups + group/chunk bounding circles + erf norm.
// Grid barrier (1024 co-resident blocks, device-scope counter, counter
// zeroed by a hipMemsetAsync node each launch).
// Phase B (1024 blocks = batch x 16x16-pt tile x sample-quarter): stage 4
// chunks (16 KB), per-chunk 64-group ballot, ctz loop unrolled x2, packed
// fp32 math, raw v_exp_f32; one atomicAdd per (point, quarter).

#define W_CONST  (-72.13475204444817f)   // -50 * log2(e)
#define RCUT     0.44060f                // d > RCUT => t <= -14 => dropped
#define PR       0.23400f                // 8x8-point wave patch half-diag + margin
#define TILE_R   0.50200f                // 16x16-point tile half-diag + margin
#define SQ50     7.07106781f             // sqrt(50)
#define AE       21.3802390f             // sqrt(50)*(3 + h/2)
#define K2       2.65284825f             // (127/6)*0.5*sqrt(pi/50)

constexpr int Bc = 4, Nc = 4096, Mc = 128 * 128, Wg = 128;
constexpr int NBLK = 1024;               // grid size (co-resident)
constexpr float Hh = 6.0f / 127.0f;      // grid spacing

typedef float f2 __attribute__((ext_vector_type(2)));

__device__ __forceinline__ float fexp2(float x) {
#if __has_builtin(__builtin_amdgcn_exp2f)
    return __builtin_amdgcn_exp2f(x);        // raw v_exp_f32
#else
    float r; asm("v_exp_f32 %0, %1" : "=v"(r) : "v"(x)); return r;
#endif
}
__device__ __forceinline__ f2 pkfma(f2 a, f2 b, f2 c) {
    return __builtin_elementwise_fma(a, b, c);   // v_pk_fma_f32
}

// Morton (Z-order) bin index: compact 2-D locality for sorted chunks.
__device__ __forceinline__ int bin_of(float x, float y) {
    int ix = (int)((x + 3.0f) * (16.0f / 6.0f));
    int iy = (int)((y + 3.0f) * (16.0f / 6.0f));
    ix = ix < 0 ? 0 : (ix > 15 ? 15 : ix);
    iy = iy < 0 ? 0 : (iy > 15 ? 15 : iy);
    ix = (ix | (ix << 2)) & 0x33; ix = (ix | (ix << 1)) & 0x55;
    iy = (iy | (iy << 2)) & 0x33; iy = (iy | (iy << 1)) & 0x55;
    return ix | (iy << 1);
}

union SMem {
    struct { int cnt[256]; int cur[256]; float4 sorted[1024]; } a;  // 18 KB
    struct { float4 sh4[768]; float4 gm[256]; } b;                  // 16 KB
};

__global__ __launch_bounds__(256, 6) void kde_fused(
        const float2* __restrict__ samples, float4* __restrict__ pk,
        float4* __restrict__ gmeta, float4* __restrict__ cmeta,
        float* __restrict__ normg, unsigned int* __restrict__ ctr,
        float* __restrict__ out) {
    __shared__ SMem sm;
    const int bid = blockIdx.x;
    const int tid = threadIdx.x;
    const int lane = tid & 63, wave = tid >> 6;

    // Zero my slice of out (Bc*Mc = 16384 float4 over 1024 blocks).
    if (tid < 16) ((float4*)out)[bid * 16 + tid] = make_float4(0, 0, 0, 0);

    if (bid < 16) {   // ===== phase A: sort segment bid =====
        const int seg = bid, bs = seg >> 2;
        float2 vv[4]; int bins[4];
        sm.a.cnt[tid] = 0;
        __syncthreads();
#pragma unroll
        for (int i = 0; i < 4; ++i) {
            vv[i] = samples[seg * 1024 + tid + 256 * i];
            bins[i] = bin_of(vv[i].x, vv[i].y);
            atomicAdd(&sm.a.cnt[bins[i]], 1);
        }
        __syncthreads();
        if (tid < 64) {   // single-wave exclusive scan over 256 bins
            const int c0 = sm.a.cnt[4 * tid], c1 = sm.a.cnt[4 * tid + 1];
            const int c2 = sm.a.cnt[4 * tid + 2], c3 = sm.a.cnt[4 * tid + 3];
            const int s0 = c0, s1 = s0 + c1, s2 = s1 + c2, s3 = s2 + c3;
            int scan = s3;
#pragma unroll
            for (int off = 1; off < 64; off <<= 1) {
                const int u = __shfl_up(scan, off, 64);
                if (tid >= off) scan += u;
            }
            const int prefix = scan - s3;
            sm.a.cur[4 * tid] = prefix;
            sm.a.cur[4 * tid + 1] = prefix + s0;
            sm.a.cur[4 * tid + 2] = prefix + s1;
            sm.a.cur[4 * tid + 3] = prefix + s2;
        }
        __syncthreads();
#pragma unroll
        for (int i = 0; i < 4; ++i) {
            const int pos = atomicAdd(&sm.a.cur[bins[i]], 1);
            sm.a.sorted[pos] = make_float4(vv[i].x, vv[i].y,
                W_CONST * (vv[i].x * vv[i].x + vv[i].y * vv[i].y), 0.f);
        }
        __syncthreads();
        {   // one group (4 sorted samples) per thread
            const float4* g = &sm.a.sorted[4 * tid];
            const float4 s0 = g[0], s1 = g[1], s2 = g[2], s3 = g[3];
            const int base = (seg * 256 + tid) * 3;
            pk[base + 0] = make_float4(s0.x, s1.x, s0.y, s1.y);
            pk[base + 1] = make_float4(s0.z, s1.z, s2.x, s3.x);
            pk[base + 2] = make_float4(s2.y, s3.y, s2.z, s3.z);
            float mnx = fminf(fminf(s0.x, s1.x), fminf(s2.x, s3.x));
            float mxx = fmaxf(fmaxf(s0.x, s1.x), fmaxf(s2.x, s3.x));
            float mny = fminf(fminf(s0.y, s1.y), fminf(s2.y, s3.y));
            float mxy = fmaxf(fmaxf(s0.y, s1.y), fmaxf(s2.y, s3.y));
            float ex = 0.5f * (mxx - mnx), ey = 0.5f * (mxy - mny);
            float r = sqrtf(ex * ex + ey * ey);
            gmeta[seg * 256 + tid] =
                make_float4(0.5f * (mnx + mxx), 0.5f * (mny + mxy), RCUT + r, r);
            float cmnx = mnx, cmxx = mxx, cmny = mny, cmxy = mxy;
#pragma unroll
            for (int off = 1; off < 64; off <<= 1) {
                cmnx = fminf(cmnx, __shfl_xor(cmnx, off, 64));
                cmxx = fmaxf(cmxx, __shfl_xor(cmxx, off, 64));
                cmny = fminf(cmny, __shfl_xor(cmny, off, 64));
                cmxy = fmaxf(cmxy, __shfl_xor(cmxy, off, 64));
            }
            if (lane == 0) {   // wave w = chunk w of this segment
                float cex = 0.5f * (cmxx - cmnx), cey = 0.5f * (cmxy - cmny);
                cmeta[seg * 4 + wave] =
                    make_float4(0.5f * (cmnx + cmxx), 0.5f * (cmny + cmxy),
                                RCUT + sqrtf(cex * cex + cey * cey), 0.f);
            }
        }
        // Analytic normalizer: norm_b = sum_n S(x)S(y)
        float psum = 0.f;
#pragma unroll
        for (int i = 0; i < 4; ++i) {
            const float sx = K2 * (erff(AE - SQ50 * vv[i].x) + erff(AE + SQ50 * vv[i].x));
            const float sy = K2 * (erff(AE - SQ50 * vv[i].y) + erff(AE + SQ50 * vv[i].y));
            psum += sx * sy;
        }
#pragma unroll
        for (int off = 32; off > 0; off >>= 1) psum += __shfl_down(psum, off, 64);
        if (lane == 0) atomicAdd(&normg[bs], psum);
    }

    // ===== grid barrier (all 1024 blocks co-resident) =====
    __threadfence();
    __syncthreads();
    if (tid == 0) {
        __hip_atomic_fetch_add(ctr, 1u, __ATOMIC_ACQ_REL, __HIP_MEMORY_SCOPE_AGENT);
        while (__hip_atomic_load(ctr, __ATOMIC_ACQUIRE, __HIP_MEMORY_SCOPE_AGENT) < NBLK)
            __builtin_amdgcn_s_sleep(4);
    }
    __syncthreads();

    // ===== phase B: (batch, 16x16 tile, sample-quarter) =====
    const int tile = bid & 63;               // fastest -> XCD spread
    const int b    = (bid >> 6) & 3;
    const int q    = bid >> 8;               // quarter: chunks q*4..q*4+3
    const int ti = tile >> 3, tj = tile & 7;

    const float tcx = -3.0f + ((float)(ti * 16) + 7.5f) * Hh;
    const float tcy = -3.0f + ((float)(tj * 16) + 7.5f) * Hh;
    const float4 cmv = cmeta[b * 16 + q * 4 + (lane & 3)];
    const float cdx = tcx - cmv.x, cdy = tcy - cmv.y;
    const float crr = cmv.z + TILE_R;
    const unsigned long long cb =
        __ballot((lane < 4) && (cdx * cdx + cdy * cdy <= crr * crr));
    if ((cb & 0xFull) == 0) return;

    const int gbase = b * 1024 + q * 256;    // first group of the quarter
#pragma unroll
    for (int i = 0; i < 3; ++i)
        sm.b.sh4[tid + 256 * i] = pk[gbase * 3 + tid + 256 * i];
    sm.b.gm[tid] = gmeta[gbase + tid];

    const int wi = wave >> 1, wj = wave & 1;
    const int gi = ti * 16 + wi * 8 + (lane >> 3);
    const int gj = tj * 16 + wj * 8 + (lane & 7);
    const int m = gi * Wg + gj;
    const float lx = (float)(-3.0 + gi * (6.0 / 127.0));
    const float ly = (float)(-3.0 + gj * (6.0 / 127.0));
    const f2 axv = (f2)(-2.0f * W_CONST * lx);
    const f2 ayv = (f2)(-2.0f * W_CONST * ly);
    const f2 c0v = (f2)(W_CONST * (lx * lx + ly * ly));
    const float pcx = -3.0f + ((float)(ti * 16 + wi * 8) + 3.5f) * Hh;
    const float pcy = -3.0f + ((float)(tj * 16 + wj * 8) + 3.5f) * Hh;

    __syncthreads();   // staging complete; LDS read-only below

    float a0 = 0.f, a1 = 0.f, a2 = 0.f, a3 = 0.f;
#pragma unroll
    for (int c = 0; c < 4; ++c) {
        const float4 gv = sm.b.gm[c * 64 + lane];
        const float gdx = pcx - gv.x, gdy = pcy - gv.y;
        const float grr = gv.z + PR;
        unsigned long long gmask = __ballot(gdx * gdx + gdy * gdy <= grr * grr);
        while (gmask) {
            const int g0 = c * 64 + __builtin_ctzll(gmask);
            gmask &= gmask - 1;
            const bool has1 = (gmask != 0);
            int g1 = g0;
            if (has1) { g1 = c * 64 + __builtin_ctzll(gmask); gmask &= gmask - 1; }
            const float4 A0 = sm.b.sh4[3 * g0 + 0];   // broadcast reads
            const float4 B0 = sm.b.sh4[3 * g0 + 1];
            const float4 C0 = sm.b.sh4[3 * g0 + 2];
            const float4 A1 = sm.b.sh4[3 * g1 + 0];
            const float4 B1 = sm.b.sh4[3 * g1 + 1];
            const float4 C1 = sm.b.sh4[3 * g1 + 2];
            const f2 x01a = {A0.x, A0.y}, y01a = {A0.z, A0.w};
            const f2 z01a = {B0.x, B0.y}, x23a = {B0.z, B0.w};
            const f2 y23a = {C0.x, C0.y}, z23a = {C0.z, C0.w};
            f2 t01a = pkfma(axv, x01a, pkfma(ayv, y01a, z01a) + c0v);
            f2 t23a = pkfma(axv, x23a, pkfma(ayv, y23a, z23a) + c0v);
            const f2 x01b = {A1.x, A1.y}, y01b = {A1.z, A1.w};
            const f2 z01b = {B1.x, B1.y}, x23b = {B1.z, B1.w};
            const f2 y23b = {C1.x, C1.y}, z23b = {C1.z, C1.w};
            f2 t01b = pkfma(axv, x01b, pkfma(ayv, y01b, z01b) + c0v);
            f2 t23b = pkfma(axv, x23b, pkfma(ayv, y23b, z23b) + c0v);
            if (!has1) { t01b = (f2)(-1000.0f); t23b = (f2)(-1000.0f); }
            a0 += fexp2(t01a.x); a1 += fexp2(t01a.y);
            a2 += fexp2(t23a.x); a3 += fexp2(t23a.y);
            a0 += fexp2(t01b.x); a1 += fexp2(t01b.y);
            a2 += fexp2(t23b.x); a3 += fexp2(t23b.y);
        }
    }

    const float acc = (a0 + a1) + (a2 + a3);
    if (acc != 0.0f) {
        const float nv = __hip_atomic_load(&normg[b], __ATOMIC_RELAXED,
                                           __HIP_MEMORY_SCOPE_AGENT);
        atomicAdd(&out[b * Mc + m], acc * (1.0f / nv));
    }
}

extern "C" void kernel_launch(void* const* d_in, const int* in_sizes, int n_in,
                              void* d_out, int out_size, void* d_ws, size_t ws_size,
                              hipStream_t stream) {
    const float* samples = (const float*)d_in[0];   // (B, N, 2) fp32
    float* out = (float*)d_out;                     // (B, H, W) fp32

    char* ws = (char*)d_ws;
    float4* pk    = (float4*)(ws);                  // 4096 groups * 48 B
    float4* gmeta = (float4*)(ws + 196608);         //  65536 B
    float4* cmeta = (float4*)(ws + 262144);         //   1024 B
    float*  normg = (float*)(ws + 263168);          //     16 B
    unsigned int* ctr = (unsigned int*)(ws + 263296);  // own 128B line

    hipMemsetAsync(ws + 263168, 0, 256, stream);    // zero normg + ctr
    kde_fused<<<NBLK, 256, 0, stream>>>((const float2*)samples, pk, gmeta,
                                        cmeta, normg, ctr, out);
}

// Round 9
// 133.932 us; speedup vs baseline: 1.0888x; 1.0888x over previous
//
#include <hip/hip_runtime.h>
#include <math.h>

// KDE Gaussian, bandwidth 0.1 — SEPARABLE rank-1 reformulation.
//   exp(-50*((x-sx)^2+(y-sy)^2)) = fx(i)*fy(j),  fx(i)=exp2(W*(xi-sx)^2)
//   => out_b = Fx_b^T (128 x 4096) * Fy_b (4096 x 128)   — a GEMM.
// Each of the 4.2M table entries is computed exactly once (raw v_exp_f32;
// entries underflow to 0 beyond |d|>1.32 naturally). 537 MFLOP of fp32
// pk-fma. No sorting, no culling, no ballots: perfectly uniform blocks.
// Normalizer analytic (validated in R8): norm_b = sum_n S(x_n)S(y_n),
//   S(u) = K2*(erf(AE-sq50*u)+erf(AE+sq50*u))   (lattice Gaussian sum).
// kde_gemm: 256 blocks = (batch, K-chunk of 64 samples). Tables in LDS
// (64.5 KB), 8x8 register tile per thread, atomicAdd into 8 slices.
// kde_fin: reduce 8 slices + divide by norm. One 2 MB memset zeroes slices.

#define W_CONST (-72.13475204444817f)   // -50 * log2(e)
#define SQ50    7.07106781f             // sqrt(50)
#define AE      21.3802390f             // sqrt(50)*(3 + h/2)
#define K2      2.65284825f             // (127/6)*0.5*sqrt(pi/50)

constexpr int Bc = 4, Nc = 4096, Mc = 128 * 128;
constexpr int KC = 64;                  // samples per chunk
constexpr int NSLICE = 8;               // partial slices (8-way atomics)
constexpr float Hh = 6.0f / 127.0f;     // grid spacing

typedef float f2 __attribute__((ext_vector_type(2)));

__device__ __forceinline__ float fexp2(float x) {
#if __has_builtin(__builtin_amdgcn_exp2f)
    return __builtin_amdgcn_exp2f(x);        // raw v_exp_f32
#else
    float r; asm("v_exp_f32 %0, %1" : "=v"(r) : "v"(x)); return r;
#endif
}
__device__ __forceinline__ f2 pkfma(f2 a, f2 b, f2 c) {
    return __builtin_elementwise_fma(a, b, c);   // v_pk_fma_f32
}

__global__ __launch_bounds__(256) void kde_gemm(
        const float2* __restrict__ samples, float* __restrict__ partial,
        float* __restrict__ normg) {
    __shared__ float2 smp[KC];
    __shared__ float fx[KC][128];   // 32 KB
    __shared__ float fy[KC][128];   // 32 KB

    const int bid = blockIdx.x;
    const int b = bid >> 6, kc = bid & 63;
    const int tid = threadIdx.x, lane = tid & 63;

    if (tid < KC) smp[tid] = samples[b * Nc + kc * KC + tid];
    __syncthreads();

    // Build fx/fy tables: 64 samples x 128 grid coords, float4 per store.
#pragma unroll
    for (int r = 0; r < 8; ++r) {
        const int idx = r * 256 + tid;       // 0..2047
        const int n = idx >> 5, i0 = (idx & 31) << 2;
        const float2 s = smp[n];             // LDS broadcast
        float4 vx, vy;
#pragma unroll
        for (int k = 0; k < 4; ++k) {
            const float xi = -3.0f + (float)(i0 + k) * Hh;
            const float dx = xi - s.x, dy = xi - s.y;
            ((float*)&vx)[k] = fexp2(W_CONST * dx * dx);
            ((float*)&vy)[k] = fexp2(W_CONST * dy * dy);
        }
        *(float4*)&fx[n][i0] = vx;
        *(float4*)&fy[n][i0] = vy;
    }

    // Analytic per-chunk normalizer partial (one wave).
    if (tid < KC) {
        const float2 s = smp[tid];
        const float sx = K2 * (erff(AE - SQ50 * s.x) + erff(AE + SQ50 * s.x));
        const float sy = K2 * (erff(AE - SQ50 * s.y) + erff(AE + SQ50 * s.y));
        float p = sx * sy;
#pragma unroll
        for (int off = 32; off > 0; off >>= 1) p += __shfl_down(p, off, 64);
        if (lane == 0) atomicAdd(&normg[b], p);
    }
    __syncthreads();

    // GEMM: thread = 8x8 output tile; acc[r][c-pair] in registers.
    const int R = (tid >> 4) * 8, C = (tid & 15) * 8;
    f2 acc[8][4];
#pragma unroll
    for (int r = 0; r < 8; ++r)
#pragma unroll
        for (int c = 0; c < 4; ++c) acc[r][c] = (f2)(0.0f);

#pragma unroll 2
    for (int n = 0; n < KC; ++n) {
        const float4 fxa = *(const float4*)&fx[n][R];
        const float4 fxb = *(const float4*)&fx[n][R + 4];
        const float4 fya = *(const float4*)&fy[n][C];
        const float4 fyb = *(const float4*)&fy[n][C + 4];
        const f2 y0 = {fya.x, fya.y}, y1 = {fya.z, fya.w};
        const f2 y2 = {fyb.x, fyb.y}, y3 = {fyb.z, fyb.w};
        const float xr[8] = {fxa.x, fxa.y, fxa.z, fxa.w,
                             fxb.x, fxb.y, fxb.z, fxb.w};
#pragma unroll
        for (int r = 0; r < 8; ++r) {        // all indices compile-time
            const f2 xv = (f2)(xr[r]);
            acc[r][0] = pkfma(xv, y0, acc[r][0]);
            acc[r][1] = pkfma(xv, y1, acc[r][1]);
            acc[r][2] = pkfma(xv, y2, acc[r][2]);
            acc[r][3] = pkfma(xv, y3, acc[r][3]);
        }
    }

    // Accumulate into slice (kc & 7): 8 contributors per address.
    float* P = partial + ((size_t)(kc & (NSLICE - 1)) * Bc + b) * Mc;
#pragma unroll
    for (int r = 0; r < 8; ++r) {
        float* row = P + (R + r) * 128 + C;
#pragma unroll
        for (int c = 0; c < 4; ++c) {
            atomicAdd(row + 2 * c,     acc[r][c].x);
            atomicAdd(row + 2 * c + 1, acc[r][c].y);
        }
    }
}

__global__ __launch_bounds__(256) void kde_fin(
        const float4* __restrict__ partial4, const float* __restrict__ normg,
        float4* __restrict__ out4) {
    const int f = blockIdx.x * 256 + threadIdx.x;   // 0..16383 (Bc*Mc/4)
    const int b = f >> 12;
    const float inv = 1.0f / normg[b];
    float sx = 0.f, sy = 0.f, sz = 0.f, sw = 0.f;
#pragma unroll
    for (int sl = 0; sl < NSLICE; ++sl) {
        const float4 v = partial4[(size_t)(sl * Bc + b) * 4096 + (f & 4095)];
        sx += v.x; sy += v.y; sz += v.z; sw += v.w;
    }
    out4[f] = make_float4(sx * inv, sy * inv, sz * inv, sw * inv);
}

extern "C" void kernel_launch(void* const* d_in, const int* in_sizes, int n_in,
                              void* d_out, int out_size, void* d_ws, size_t ws_size,
                              hipStream_t stream) {
    const float* samples = (const float*)d_in[0];   // (B, N, 2) fp32
    float* out = (float*)d_out;                     // (B, H, W) fp32

    char* ws = (char*)d_ws;
    float* partial = (float*)ws;                    // 8*4*16384*4 B = 2 MB
    float* normg   = (float*)(ws + 2097152);        // 16 B

    hipMemsetAsync(ws, 0, 2097152 + 64, stream);    // slices + normg
    kde_gemm<<<Bc * 64, 256, 0, stream>>>((const float2*)samples, partial, normg);
    kde_fin <<<Bc * Mc / 4 / 256, 256, 0, stream>>>((const float4*)partial,
                                                    normg, (float4*)out);
}

// Round 10
// 33.587 us; speedup vs baseline: 4.3416x; 3.9876x over previous
//
#include <hip/hip_runtime.h>
#include <math.h>

// KDE Gaussian, bandwidth 0.1 — SEPARABLE rank-1 reformulation.
//   exp(-50*((x-sx)^2+(y-sy)^2)) = fx(i)*fy(j)  =>  out_b = Fx_b^T * Fy_b.
// 4.2M table exps (each entry exactly once, raw v_exp_f32) + 134M pk-fma.
// R9 lesson: NO global atomics for accumulation (each fp32 atomicAdd cost
// ~32B of memory-side RMW traffic -> 134MB writes, 140us). Instead each
// (b, K-chunk) block owns a PRIVATE partial slice (plain float4 stores,
// 16MB total) and kde_fin reduces 64 slices + divides by analytic norm:
//   norm_b = sum_n S(x_n)S(y_n), S(u) = K2*(erf(AE-sq50 u)+erf(AE+sq50 u)).

#define W_CONST (-72.13475204444817f)   // -50 * log2(e)
#define SQ50    7.07106781f             // sqrt(50)
#define AE      21.3802390f             // sqrt(50)*(3 + h/2)
#define K2      2.65284825f             // (127/6)*0.5*sqrt(pi/50)

constexpr int Bc = 4, Nc = 4096, Mc = 128 * 128;
constexpr int KC = 64;                  // samples per chunk
constexpr int NCH = Nc / KC;            // 64 chunks -> 64 private slices
constexpr float Hh = 6.0f / 127.0f;     // grid spacing

typedef float f2 __attribute__((ext_vector_type(2)));

__device__ __forceinline__ float fexp2(float x) {
#if __has_builtin(__builtin_amdgcn_exp2f)
    return __builtin_amdgcn_exp2f(x);        // raw v_exp_f32
#else
    float r; asm("v_exp_f32 %0, %1" : "=v"(r) : "v"(x)); return r;
#endif
}
__device__ __forceinline__ f2 pkfma(f2 a, f2 b, f2 c) {
    return __builtin_elementwise_fma(a, b, c);   // v_pk_fma_f32
}

__global__ __launch_bounds__(256) void kde_gemm(
        const float2* __restrict__ samples, float* __restrict__ partial,
        float* __restrict__ normg) {
    __shared__ float2 smp[KC];
    __shared__ float fx[KC][128];   // 32 KB
    __shared__ float fy[KC][128];   // 32 KB

    const int bid = blockIdx.x;
    const int b = bid >> 6, kc = bid & 63;
    const int tid = threadIdx.x, lane = tid & 63;

    if (tid < KC) smp[tid] = samples[b * Nc + kc * KC + tid];
    __syncthreads();

    // Build fx/fy tables: 64 samples x 128 grid coords, float4 per store.
#pragma unroll
    for (int r = 0; r < 8; ++r) {
        const int idx = r * 256 + tid;       // 0..2047
        const int n = idx >> 5, i0 = (idx & 31) << 2;
        const float2 s = smp[n];             // LDS broadcast
        float4 vx, vy;
#pragma unroll
        for (int k = 0; k < 4; ++k) {
            const float xi = -3.0f + (float)(i0 + k) * Hh;
            const float dx = xi - s.x, dy = xi - s.y;
            ((float*)&vx)[k] = fexp2(W_CONST * dx * dx);
            ((float*)&vy)[k] = fexp2(W_CONST * dy * dy);
        }
        *(float4*)&fx[n][i0] = vx;
        *(float4*)&fy[n][i0] = vy;
    }

    // Analytic per-chunk normalizer partial (one wave; 256 atomics total).
    if (tid < KC) {
        const float2 s = smp[tid];
        const float sx = K2 * (erff(AE - SQ50 * s.x) + erff(AE + SQ50 * s.x));
        const float sy = K2 * (erff(AE - SQ50 * s.y) + erff(AE + SQ50 * s.y));
        float p = sx * sy;
#pragma unroll
        for (int off = 32; off > 0; off >>= 1) p += __shfl_down(p, off, 64);
        if (lane == 0) atomicAdd(&normg[b], p);
    }
    __syncthreads();

    // GEMM: thread = 8x8 output tile; acc in registers.
    const int R = (tid >> 4) * 8, C = (tid & 15) * 8;
    f2 acc[8][4];
#pragma unroll
    for (int r = 0; r < 8; ++r)
#pragma unroll
        for (int c = 0; c < 4; ++c) acc[r][c] = (f2)(0.0f);

#pragma unroll 2
    for (int n = 0; n < KC; ++n) {
        const float4 fxa = *(const float4*)&fx[n][R];
        const float4 fxb = *(const float4*)&fx[n][R + 4];
        const float4 fya = *(const float4*)&fy[n][C];
        const float4 fyb = *(const float4*)&fy[n][C + 4];
        const f2 y0 = {fya.x, fya.y}, y1 = {fya.z, fya.w};
        const f2 y2 = {fyb.x, fyb.y}, y3 = {fyb.z, fyb.w};
        const float xr[8] = {fxa.x, fxa.y, fxa.z, fxa.w,
                             fxb.x, fxb.y, fxb.z, fxb.w};
#pragma unroll
        for (int r = 0; r < 8; ++r) {        // all indices compile-time
            const f2 xv = (f2)(xr[r]);
            acc[r][0] = pkfma(xv, y0, acc[r][0]);
            acc[r][1] = pkfma(xv, y1, acc[r][1]);
            acc[r][2] = pkfma(xv, y2, acc[r][2]);
            acc[r][3] = pkfma(xv, y3, acc[r][3]);
        }
    }

    // Plain coalesced stores into this block's PRIVATE slice. No atomics.
    float* P = partial + ((size_t)kc * Bc + b) * Mc;
#pragma unroll
    for (int r = 0; r < 8; ++r) {
        float* row = P + (R + r) * 128 + C;
        *(float4*)(row)     = make_float4(acc[r][0].x, acc[r][0].y,
                                          acc[r][1].x, acc[r][1].y);
        *(float4*)(row + 4) = make_float4(acc[r][2].x, acc[r][2].y,
                                          acc[r][3].x, acc[r][3].y);
    }
}

__global__ __launch_bounds__(256) void kde_fin(
        const float4* __restrict__ partial4, const float* __restrict__ normg,
        float4* __restrict__ out4) {
    const int f = blockIdx.x * 256 + threadIdx.x;   // 0..16383 (Bc*Mc/4)
    const int b = f >> 12;
    const float inv = 1.0f / normg[b];
    float sx = 0.f, sy = 0.f, sz = 0.f, sw = 0.f;
#pragma unroll 8
    for (int sl = 0; sl < NCH; ++sl) {
        const float4 v = partial4[(size_t)(sl * Bc + b) * 4096 + (f & 4095)];
        sx += v.x; sy += v.y; sz += v.z; sw += v.w;
    }
    out4[f] = make_float4(sx * inv, sy * inv, sz * inv, sw * inv);
}

extern "C" void kernel_launch(void* const* d_in, const int* in_sizes, int n_in,
                              void* d_out, int out_size, void* d_ws, size_t ws_size,
                              hipStream_t stream) {
    const float* samples = (const float*)d_in[0];   // (B, N, 2) fp32
    float* out = (float*)d_out;                     // (B, H, W) fp32

    char* ws = (char*)d_ws;
    float* partial = (float*)ws;                    // 64*4*16384*4 B = 16 MB
    float* normg   = (float*)(ws + (size_t)16777216);  // 16 B

    hipMemsetAsync(normg, 0, 64, stream);           // just the normalizer
    kde_gemm<<<Bc * NCH, 256, 0, stream>>>((const float2*)samples, partial, normg);
    kde_fin <<<Bc * Mc / 4 / 256, 256, 0, stream>>>((const float4*)partial,
                                                    normg, (float4*)out);
}

// Round 11
// 26.686 us; speedup vs baseline: 5.4644x; 1.2586x over previous
//
#include <hip/hip_runtime.h>
#include <math.h>

// KDE Gaussian, bandwidth 0.1 — separable reformulation, 2-dispatch graph.
//   exp(-50*((x-sx)^2+(y-sy)^2)) = fx(i)*fy(j)  =>  out_b = Fx_b^T * Fy_b.
// kde_gemm: 128 blocks = (batch, K-chunk of 128 samples), 512 threads.
//   Full fx/fy tables for the chunk live in LDS (129 KB, 1 block/CU, 8
//   waves = 2/SIMD).  Per K-step: 1 broadcast b128 (fx) + 2 swizzled b128
//   (fy, 2-way banks = free) + 16 v_pk_fma_f32.  Private 64 KB partial
//   slice per block (plain stores — R9 lesson: global atomics cost ~32B
//   RMW traffic each).  Analytic erf normalizer partial per block (plain
//   store; no atomics, no memset anywhere).
// kde_fin: 128 blocks x 128 thr: sum 32 slices + scale by 1/norm.
//   norm_b = sum_n S(x_n)S(y_n), S(u) = K2*(erf(AE-sq50 u)+erf(AE+sq50 u))
//   (lattice Gaussian sum, validated R8-R10).

#define W_CONST (-72.13475204444817f)   // -50 * log2(e)
#define SQ50    7.07106781f             // sqrt(50)
#define AE      21.3802390f             // sqrt(50)*(3 + h/2)
#define K2      2.65284825f             // (127/6)*0.5*sqrt(pi/50)

constexpr int Bc = 4, Nc = 4096, Mc = 128 * 128;
constexpr int KC = 128;                 // samples per chunk
constexpr int NCHK = Nc / KC;           // 32 chunks/batch -> 32 slices
constexpr float Hh = 6.0f / 127.0f;     // grid spacing

typedef float f2 __attribute__((ext_vector_type(2)));

__device__ __forceinline__ float fexp2(float x) {
#if __has_builtin(__builtin_amdgcn_exp2f)
    return __builtin_amdgcn_exp2f(x);        // raw v_exp_f32
#else
    float r; asm("v_exp_f32 %0, %1" : "=v"(r) : "v"(x)); return r;
#endif
}
__device__ __forceinline__ f2 pkfma(f2 a, f2 b, f2 c) {
    return __builtin_elementwise_fma(a, b, c);   // v_pk_fma_f32
}
// fy column-slot swizzle: even float4-slots -> 0..15, odd -> 16..31.
// Read set {2v} maps to {v} (2-way banks = free), {2v+1} -> {16+v} (2-way).
__device__ __forceinline__ int sgm(int fq) {
    return (fq >> 1) | ((fq & 1) << 4);
}

__global__ __launch_bounds__(512) void kde_gemm(
        const float2* __restrict__ samples, float* __restrict__ partial,
        float* __restrict__ normp) {
    __shared__ float2 smp[KC];          //   1 KB
    __shared__ float4 fx4[KC][32];      //  64 KB
    __shared__ float4 fy4[KC][32];      //  64 KB

    const int bid = blockIdx.x;
    const int b = bid >> 5, kc = bid & 31;
    const int tid = threadIdx.x;

    if (tid < KC) smp[tid] = samples[b * Nc + kc * KC + tid];
    __syncthreads();

    // Build tables: 128 samples x 128 coords x 2; 8 float4-pairs/thread.
#pragma unroll
    for (int r = 0; r < 8; ++r) {
        const int idx = r * 512 + tid;       // 0..4095
        const int n = idx >> 5, fq = idx & 31, i0 = fq << 2;
        const float2 s = smp[n];             // LDS broadcast
        float4 vx, vy;
#pragma unroll
        for (int k = 0; k < 4; ++k) {
            const float xi = -3.0f + (float)(i0 + k) * Hh;
            const float dx = xi - s.x, dy = xi - s.y;
            ((float*)&vx)[k] = fexp2(W_CONST * dx * dx);
            ((float*)&vy)[k] = fexp2(W_CONST * dy * dy);
        }
        fx4[n][fq] = vx;
        fy4[n][sgm(fq)] = vy;                // swizzled store
    }

    // Analytic normalizer partial for this chunk (wave 0; plain store).
    if (tid < 64) {
        const float2 sa = smp[tid], sb = smp[tid + 64];
        const float xa = K2 * (erff(AE - SQ50 * sa.x) + erff(AE + SQ50 * sa.x));
        const float ya = K2 * (erff(AE - SQ50 * sa.y) + erff(AE + SQ50 * sa.y));
        const float xb = K2 * (erff(AE - SQ50 * sb.x) + erff(AE + SQ50 * sb.x));
        const float yb = K2 * (erff(AE - SQ50 * sb.y) + erff(AE + SQ50 * sb.y));
        float p = xa * ya + xb * yb;
#pragma unroll
        for (int off = 32; off > 0; off >>= 1) p += __shfl_down(p, off, 64);
        if (tid == 0) normp[bid] = p;
    }
    __syncthreads();

    // GEMM: thread = 4 rows x 8 cols; acc in registers.
    const int u = tid >> 4, v = tid & 15;    // u: 0..31 rows/4, v: 0..15 cols/8
    const int c0 = sgm(2 * v), c1 = sgm(2 * v + 1);
    f2 acc[4][4];
#pragma unroll
    for (int r = 0; r < 4; ++r)
#pragma unroll
        for (int c = 0; c < 4; ++c) acc[r][c] = (f2)(0.0f);

#pragma unroll 4
    for (int n = 0; n < KC; ++n) {
        const float4 xv = fx4[n][u];         // broadcast across 16 lanes
        const float4 ya = fy4[n][c0];        // 2-way banks (free)
        const float4 yb = fy4[n][c1];
        const f2 y0 = {ya.x, ya.y}, y1 = {ya.z, ya.w};
        const f2 y2 = {yb.x, yb.y}, y3 = {yb.z, yb.w};
        const float xr[4] = {xv.x, xv.y, xv.z, xv.w};
#pragma unroll
        for (int r = 0; r < 4; ++r) {
            const f2 x = (f2)(xr[r]);
            acc[r][0] = pkfma(x, y0, acc[r][0]);
            acc[r][1] = pkfma(x, y1, acc[r][1]);
            acc[r][2] = pkfma(x, y2, acc[r][2]);
            acc[r][3] = pkfma(x, y3, acc[r][3]);
        }
    }

    // Plain coalesced stores into this block's private slice.
    float* P = partial + (size_t)bid * Mc;
    const int R = u * 4, C = v * 8;
#pragma unroll
    for (int r = 0; r < 4; ++r) {
        float* row = P + (R + r) * 128 + C;
        *(float4*)(row)     = make_float4(acc[r][0].x, acc[r][0].y,
                                          acc[r][1].x, acc[r][1].y);
        *(float4*)(row + 4) = make_float4(acc[r][2].x, acc[r][2].y,
                                          acc[r][3].x, acc[r][3].y);
    }
}

__global__ __launch_bounds__(128) void kde_fin(
        const float4* __restrict__ partial4, const float* __restrict__ normp,
        float4* __restrict__ out4) {
    const int f = blockIdx.x * 128 + threadIdx.x;   // 0..16383 (Bc*Mc/4)
    const int b = f >> 12, col = f & 4095;
    float nsum = 0.f;
#pragma unroll
    for (int s = 0; s < NCHK; ++s) nsum += normp[b * NCHK + s];  // uniform
    const float inv = 1.0f / nsum;
    float sx = 0.f, sy = 0.f, sz = 0.f, sw = 0.f;
#pragma unroll 8
    for (int s = 0; s < NCHK; ++s) {
        const float4 v = partial4[(size_t)(b * NCHK + s) * 4096 + col];
        sx += v.x; sy += v.y; sz += v.z; sw += v.w;
    }
    out4[f] = make_float4(sx * inv, sy * inv, sz * inv, sw * inv);
}

extern "C" void kernel_launch(void* const* d_in, const int* in_sizes, int n_in,
                              void* d_out, int out_size, void* d_ws, size_t ws_size,
                              hipStream_t stream) {
    const float* samples = (const float*)d_in[0];   // (B, N, 2) fp32
    float* out = (float*)d_out;                     // (B, H, W) fp32

    char* ws = (char*)d_ws;
    float* partial = (float*)ws;                    // 128 slices * 64 KB = 8 MB
    float* normp   = (float*)(ws + 8388608);        // 128 floats

    kde_gemm<<<Bc * NCHK, 512, 0, stream>>>((const float2*)samples,
                                            partial, normp);
    kde_fin <<<Bc * Mc / 4 / 128, 128, 0, stream>>>((const float4*)partial,
                                                    normp, (float4*)out);
}